// Round 7
// baseline (239.548 us; speedup 1.0000x reference)
//
#include <hip/hip_runtime.h>
#include <hip/hip_bf16.h>
#include <stdint.h>

#define BB 2
#define NN 2048
#define CC 1024
#define HH 16
#define DD 64
#define C3 3072

typedef __attribute__((ext_vector_type(8))) short bf16x8;
typedef __attribute__((ext_vector_type(4))) float f32x4;
typedef __attribute__((ext_vector_type(4))) unsigned short ushort4_t;

__device__ __forceinline__ unsigned short f2bf(float f) {
  union { float f; unsigned u; } v; v.f = f;
  unsigned r = v.u + 0x7FFFu + ((v.u >> 16) & 1u);
  return (unsigned short)(r >> 16);
}

#if __has_builtin(__builtin_amdgcn_exp2f)
#define EXP2(x) __builtin_amdgcn_exp2f(x)
#else
#define EXP2(x) exp2f(x)
#endif

// 0.125 (1/sqrt(D)) * log2(e): folded into Q so softmax is raw v_exp_f32 (2^x)
#define QSCALE 0.18033688f

// async global->LDS, 16B per lane; LDS dest must be wave-uniform base + lane*16
#define GLDS(g, l) __builtin_amdgcn_global_load_lds( \
    (const __attribute__((address_space(1))) void*)(g), \
    (__attribute__((address_space(3))) void*)(l), 16, 0, 0)

// ----------------------------------------- merged fp32->bf16 converts (3 bufs)
__global__ __launch_bounds__(256) void k_cvt(
    const float* __restrict__ x, const float* __restrict__ wq,
    const float* __restrict__ wp,
    unsigned short* __restrict__ xb, unsigned short* __restrict__ wqb,
    unsigned short* __restrict__ wpb)
{
  int blk = blockIdx.x;
  const float* s; unsigned short* d; int i;
  if (blk < 4096)      { s = x;  d = xb;  i = blk * 256 + threadIdx.x; }
  else if (blk < 7168) { s = wq; d = wqb; i = (blk - 4096) * 256 + threadIdx.x; }
  else                 { s = wp; d = wpb; i = (blk - 7168) * 256 + threadIdx.x; }
  float4 v = ((const float4*)s)[i];
  ushort4_t o;
  o.x = f2bf(v.x); o.y = f2bf(v.y); o.z = f2bf(v.z); o.w = f2bf(v.w);
  ((ushort4_t*)d)[i] = o;
}

// -------------------------------- GEMM1 fused: qkv = x@Wqkv^T + b, RoPE, pack
// BK=32 m97-style K-loop (proven; BK=64 variant regressed — R6 post-mortem).
// Epilogue: each wave's 64x64 quadrant = one (region, head) tile. RoPE in
// registers (shfl_xor pair exchange), stage tile in wave-private LDS
// (XOR-swizzled, reusing staging LDS), then 8 contiguous 1KB dwordx4 stores.
// Region V is staged transposed -> writes Vt[bh][d][n] directly (no k_vt).
__global__ __launch_bounds__(256) void k_gemm_qkv(
    const unsigned short* __restrict__ A, const unsigned short* __restrict__ Bt,
    const float* __restrict__ bias,
    const float* __restrict__ cosb, const float* __restrict__ sinb,
    unsigned short* __restrict__ Qg, unsigned short* __restrict__ Kg,
    unsigned short* __restrict__ Vt)
{
  __shared__ __align__(16) unsigned short Sh[16384];  // 32KB: staging + epilogue
  unsigned short* As = Sh;           // 128 x 32
  unsigned short* Bs = Sh + 4096;    // 128 x 32
  const int tid  = threadIdx.x;
  const int lane = tid & 63;
  const int wave = tid >> 6;
  const int bm = blockIdx.y * 128;
  const int bn = blockIdx.x * 128;
  const int wm = (wave >> 1) * 64;
  const int wn = (wave & 1) * 64;
  const int frow = lane & 15;
  const int fk   = (lane >> 4) * 8;
  const int K = 1024;

  f32x4 acc[4][4] = {};

  const int row0 = tid >> 2, cc0 = tid & 3;
  const int row1 = row0 + 64;

  for (int k0 = 0; k0 < K; k0 += 32) {
    GLDS(A  + (size_t)(bm + row0) * K + k0 + cc0 * 8, As + (size_t)tid * 8);
    GLDS(Bt + (size_t)(bn + row0) * K + k0 + cc0 * 8, Bs + (size_t)tid * 8);
    GLDS(A  + (size_t)(bm + row1) * K + k0 + cc0 * 8, As + (size_t)(tid + 256) * 8);
    GLDS(Bt + (size_t)(bn + row1) * K + k0 + cc0 * 8, Bs + (size_t)(tid + 256) * 8);
    __syncthreads();

    bf16x8 af[4], bfr[4];
#pragma unroll
    for (int t = 0; t < 4; ++t) {
      af[t]  = *(const bf16x8*)(As + (wm + t * 16 + frow) * 32 + fk);
      bfr[t] = *(const bf16x8*)(Bs + (wn + t * 16 + frow) * 32 + fk);
    }
#pragma unroll
    for (int mt = 0; mt < 4; ++mt)
#pragma unroll
      for (int nt = 0; nt < 4; ++nt)
        acc[mt][nt] = __builtin_amdgcn_mfma_f32_16x16x32_bf16(af[mt], bfr[nt], acc[mt][nt], 0, 0, 0);
    __syncthreads();   // final iter: all waves done with As/Bs -> Sh reusable
  }

  const int er0  = (lane >> 4) * 4;
  const int ecol = lane & 15;
  const int region = bn >> 10;                 // wave-uniform: 0=Q,1=K,2=V
  const int gcol0 = bn + wn;                   // 64-aligned -> one head
  const int h  = (gcol0 >> 6) & 15;
  const int rowg0 = bm + wm;                   // wave-uniform
  const int b  = rowg0 >> 11;
  const int n0 = rowg0 & (NN - 1);
  unsigned short* wt = Sh + wave * 4096;       // 64x64 wave-private tile

#pragma unroll
  for (int nt = 0; nt < 4; ++nt) {
    const int c64 = nt * 16 + ecol;            // d within head
    const float bv = bias[gcol0 + c64];
    const int ii  = c64 >> 1;
#pragma unroll
    for (int mt = 0; mt < 4; ++mt)
#pragma unroll
      for (int r = 0; r < 4; ++r) {
        const int ml = mt * 16 + er0 + r;      // row within wave tile
        const int n  = n0 + ml;
        float v = acc[mt][nt][r] + bv;
        float vp = __shfl_xor(v, 1, 64);       // pair partner (d^1)
        if (region == 2) {
          // transposed tile [d][m], chunk over m swizzled by d
          wt[c64 * 64 + ((((ml >> 3) ^ (c64 & 7)) << 3) | (ml & 7))] = f2bf(v);
        } else {
          float cth = cosb[n * 32 + ii], sth = sinb[n * 32 + ii];
          float ov = (c64 & 1) ? (vp * sth + v * cth)
                               : (v * cth - vp * sth);
          if (region == 0) ov *= QSCALE;
          // tile [m][d], chunk over d swizzled by m
          wt[ml * 64 + ((((c64 >> 3) ^ (ml & 7)) << 3) | (c64 & 7))] = f2bf(ov);
        }
      }
  }

  // coalesced store phase (wave-private tile; in-wave lgkmcnt ordering)
  const int rr = lane >> 3, cc = lane & 7;
  if (region == 2) {
    unsigned short* dst = Vt + (size_t)(b * HH + h) * DD * NN + n0;
#pragma unroll
    for (int it = 0; it < 8; ++it) {
      int dl = it * 8 + rr;                    // d-row of Vt
      bf16x8 vv = *(const bf16x8*)(wt + dl * 64 + ((cc ^ (dl & 7)) << 3));
      *(bf16x8*)(dst + (size_t)dl * NN + cc * 8) = vv;
    }
  } else {
    unsigned short* dqk = ((region == 0) ? Qg : Kg) +
                          ((size_t)(b * HH + h) * NN + n0) * DD;
#pragma unroll
    for (int it = 0; it < 8; ++it) {
      int ml = it * 8 + rr;                    // n-row
      bf16x8 vv = *(const bf16x8*)(wt + ml * 64 + ((cc ^ (ml & 7)) << 3));
      *(bf16x8*)(dqk + (size_t)ml * DD + cc * 8) = vv;
    }
  }
}

// ----------------------------------------------------- flash attention v6
// kv-SPLIT: grid 1024 = bh(32) x qtile(16) x half(2); each block does half the
// kv axis (16 iters), writes UNNORMALIZED O (f32) + l partials; combine
// kernel finishes exactly (max-free softmax => partials sum exactly).
__global__ __launch_bounds__(256) void k_attn(
    const unsigned short* __restrict__ Qg, const unsigned short* __restrict__ Kg,
    const unsigned short* __restrict__ Vtg,
    float* __restrict__ Op, float* __restrict__ lp)
{
  __shared__ __align__(16) unsigned short Ks[2][64 * 64];  // [kv][d] swizzled
  __shared__ __align__(16) unsigned short Vs[2][64 * 64];  // [d][kv] swizzled
  __shared__ __align__(16) unsigned short Ps[4][32 * 32];  // per-wave [m][kv32]

  const int tid  = threadIdx.x;
  const int lane = tid & 63;
  const int wave = tid >> 6;
  const int blk  = blockIdx.x;
  const int bh   = blk >> 5;
  const int qt   = (blk >> 1) & 15;
  const int half = blk & 1;
  const int q0 = qt * 128 + wave * 32;
  const int frow   = lane & 15;
  const int fchunk = lane >> 4;
  const int er0  = (lane >> 4) * 4;
  const int ecol = lane & 15;

  const unsigned short* Qb = Qg  + (size_t)bh * NN * DD;
  const unsigned short* Kb = Kg  + (size_t)bh * NN * DD;
  const unsigned short* Vb = Vtg + (size_t)bh * DD * NN;
  const int jbase = half * (NN / 2);

  bf16x8 qf[2][2];
#pragma unroll
  for (int m = 0; m < 2; ++m)
#pragma unroll
    for (int kt = 0; kt < 2; ++kt)
      qf[m][kt] = *(const bf16x8*)(Qb + (size_t)(q0 + m * 16 + frow) * DD + kt * 32 + fchunk * 8);

  bf16x8 ones;
#pragma unroll
  for (int i = 0; i < 8; ++i) ones[i] = (short)0x3F80;

  f32x4 oacc[2][4] = {};
  f32x4 lacc[2] = {};

  const int row0 = tid >> 3, cc0 = tid & 7;
  const int sw0 = (cc0 ^ (row0 & 7)) * 8;

  GLDS(Kb + (size_t)(jbase + row0) * DD + sw0,      Ks[0] + (size_t)tid * 8);
  GLDS(Vb + (size_t)row0 * NN + jbase + sw0,        Vs[0] + (size_t)tid * 8);
  GLDS(Kb + (size_t)(jbase + row0 + 32) * DD + sw0, Ks[0] + (size_t)(tid + 256) * 8);
  GLDS(Vb + (size_t)(row0 + 32) * NN + jbase + sw0, Vs[0] + (size_t)(tid + 256) * 8);

  for (int t = 0; t < NN / 128; ++t) {
    const int p = t & 1;
    __syncthreads();

    if (t + 1 < NN / 128) {
      const int j = jbase + (t + 1) * 64;
      GLDS(Kb + (size_t)(j + row0) * DD + sw0,      Ks[1 - p] + (size_t)tid * 8);
      GLDS(Vb + (size_t)row0 * NN + j + sw0,        Vs[1 - p] + (size_t)tid * 8);
      GLDS(Kb + (size_t)(j + row0 + 32) * DD + sw0, Ks[1 - p] + (size_t)(tid + 256) * 8);
      GLDS(Vb + (size_t)(row0 + 32) * NN + j + sw0, Vs[1 - p] + (size_t)(tid + 256) * 8);
    }

    // S = Q K^T : 2 m-frags x 4 kv-frags
    f32x4 sacc[2][4] = {};
#pragma unroll
    for (int nt = 0; nt < 4; ++nt) {
      int kr = nt * 16 + frow;
      bf16x8 kf0 = *(const bf16x8*)(Ks[p] + kr * 64 + ((fchunk       ^ (kr & 7)) << 3));
      bf16x8 kf1 = *(const bf16x8*)(Ks[p] + kr * 64 + (((fchunk + 4) ^ (kr & 7)) << 3));
#pragma unroll
      for (int m = 0; m < 2; ++m) {
        sacc[m][nt] = __builtin_amdgcn_mfma_f32_16x16x32_bf16(qf[m][0], kf0, sacc[m][nt], 0, 0, 0);
        sacc[m][nt] = __builtin_amdgcn_mfma_f32_16x16x32_bf16(qf[m][1], kf1, sacc[m][nt], 0, 0, 0);
      }
    }

    // per-kh half: exp -> Ps (32x32 per wave) -> l-MFMA + PV
#pragma unroll
    for (int kh = 0; kh < 2; ++kh) {
#pragma unroll
      for (int m = 0; m < 2; ++m)
#pragma unroll
        for (int r = 0; r < 4; ++r) {
          int prow = m * 16 + er0 + r;
#pragma unroll
          for (int nh = 0; nh < 2; ++nh) {
            float pv = EXP2(sacc[m][kh * 2 + nh][r]);
            union { float f; unsigned u; } cv; cv.f = pv;
            int cl = nh * 16 + ecol;
            Ps[wave][prow * 32 + (((cl >> 3) ^ (prow & 3)) << 3) + (cl & 7)] =
                (unsigned short)(cv.u >> 16);
          }
        }

      bf16x8 pf[2];
#pragma unroll
      for (int m = 0; m < 2; ++m) {
        int pr = m * 16 + frow;
        pf[m] = *(const bf16x8*)(&Ps[wave][pr * 32 + ((fchunk ^ (pr & 3)) << 3)]);
        lacc[m] = __builtin_amdgcn_mfma_f32_16x16x32_bf16(pf[m], ones, lacc[m], 0, 0, 0);
      }
#pragma unroll
      for (int dt = 0; dt < 4; ++dt) {
        int vr = dt * 16 + frow;
        bf16x8 vf = *(const bf16x8*)(Vs[p] + vr * 64 + (((kh * 4 + fchunk) ^ (vr & 7)) << 3));
#pragma unroll
        for (int m = 0; m < 2; ++m)
          oacc[m][dt] = __builtin_amdgcn_mfma_f32_16x16x32_bf16(pf[m], vf, oacc[m][dt], 0, 0, 0);
      }
    }
  }

  // write f32 partials (unnormalized) + l
  float* Oh = Op + (size_t)half * (32u * NN * DD);
#pragma unroll
  for (int m = 0; m < 2; ++m) {
#pragma unroll
    for (int dt = 0; dt < 4; ++dt)
#pragma unroll
      for (int r = 0; r < 4; ++r) {
        int qrow = q0 + m * 16 + er0 + r;
        int d = dt * 16 + ecol;
        Oh[((size_t)bh * NN + qrow) * DD + d] = oacc[m][dt][r];
      }
    if (ecol == 0) {
#pragma unroll
      for (int r = 0; r < 4; ++r) {
        int qrow = q0 + m * 16 + er0 + r;
        lp[(size_t)half * (32 * NN) + bh * NN + qrow] = lacc[m][r];
      }
    }
  }
}

// ------------------- combine halves: aob = (Oa+Ob)/(la+lb), bf16 [b][n][c]
__global__ __launch_bounds__(256) void k_combine(
    const float* __restrict__ Op, const float* __restrict__ lp,
    unsigned short* __restrict__ aob)
{
  int idx = blockIdx.x * 256 + threadIdx.x;     // 1,048,576 = 65536 q x 16 d4
  int q  = idx >> 4;                            // bh*2048 + n
  int d4 = (idx & 15) * 4;
  const float4 a = *(const float4*)(Op + (size_t)q * DD + d4);
  const float4 b = *(const float4*)(Op + (size_t)(32u * NN * DD) + (size_t)q * DD + d4);
  float inv = 1.0f / (lp[q] + lp[32 * NN + q]);
  int bh = q >> 11, n = q & (NN - 1);
  int bb = bh >> 4, h = bh & 15;
  ushort4_t o;
  o.x = f2bf((a.x + b.x) * inv);
  o.y = f2bf((a.y + b.y) * inv);
  o.z = f2bf((a.z + b.z) * inv);
  o.w = f2bf((a.w + b.w) * inv);
  *(ushort4_t*)(aob + ((size_t)(bb * NN + n) * CC) + h * DD + d4) = o;
}

// ------------------------------- GEMM2: out = aob @ Wproj^T + b (fp32 out)
// BK=32 (reverted); 64x128 tiles, grid (8,64) = 512 blocks.
__global__ __launch_bounds__(256) void k_gemm_proj(
    const unsigned short* __restrict__ A, const unsigned short* __restrict__ Bt,
    const float* __restrict__ bias, float* __restrict__ Co)
{
  __shared__ __align__(16) unsigned short As[64 * 32];
  __shared__ __align__(16) unsigned short Bs[128 * 32];
  const int tid  = threadIdx.x;
  const int lane = tid & 63;
  const int wave = tid >> 6;
  const int bm = blockIdx.y * 64;
  const int bn = blockIdx.x * 128;
  const int wm = (wave >> 1) * 32;
  const int wn = (wave & 1) * 64;
  const int frow = lane & 15;
  const int fk   = (lane >> 4) * 8;
  const int K = 1024;

  f32x4 acc[2][4] = {};

  const int row0 = tid >> 2, cc0 = tid & 3;

  for (int k0 = 0; k0 < K; k0 += 32) {
    GLDS(A  + (size_t)(bm + row0) * K + k0 + cc0 * 8, As + (size_t)tid * 8);
    GLDS(Bt + (size_t)(bn + row0) * K + k0 + cc0 * 8, Bs + (size_t)tid * 8);
    GLDS(Bt + (size_t)(bn + row0 + 64) * K + k0 + cc0 * 8, Bs + (size_t)(tid + 256) * 8);
    __syncthreads();

    bf16x8 af[2], bfr[4];
#pragma unroll
    for (int t = 0; t < 2; ++t)
      af[t] = *(const bf16x8*)(As + (wm + t * 16 + frow) * 32 + fk);
#pragma unroll
    for (int t = 0; t < 4; ++t)
      bfr[t] = *(const bf16x8*)(Bs + (wn + t * 16 + frow) * 32 + fk);
#pragma unroll
    for (int mt = 0; mt < 2; ++mt)
#pragma unroll
      for (int nt = 0; nt < 4; ++nt)
        acc[mt][nt] = __builtin_amdgcn_mfma_f32_16x16x32_bf16(af[mt], bfr[nt], acc[mt][nt], 0, 0, 0);
    __syncthreads();
  }

  const int er0  = (lane >> 4) * 4;
  const int ecol = lane & 15;
#pragma unroll
  for (int nt = 0; nt < 4; ++nt) {
    int col = bn + wn + nt * 16 + ecol;
    float bv = bias[col];
#pragma unroll
    for (int mt = 0; mt < 2; ++mt)
#pragma unroll
      for (int r = 0; r < 4; ++r) {
        int rowg = bm + wm + mt * 16 + er0 + r;
        Co[(size_t)rowg * CC + col] = acc[mt][nt][r] + bv;
      }
  }
}

// ---------------------------------------------------------------- launcher
extern "C" void kernel_launch(void* const* d_in, const int* in_sizes, int n_in,
                              void* d_out, int out_size, void* d_ws, size_t ws_size,
                              hipStream_t stream)
{
  const float* x      = (const float*)d_in[0];
  const float* w_qkv  = (const float*)d_in[1];
  const float* b_qkv  = (const float*)d_in[2];
  const float* w_proj = (const float*)d_in[3];
  const float* b_proj = (const float*)d_in[4];
  const float* fcos   = (const float*)d_in[5];
  const float* fsin   = (const float*)d_in[6];
  float* out = (float*)d_out;

  char* ws = (char*)d_ws;
  unsigned short* xb     = (unsigned short*)(ws);              //  8 MB
  unsigned short* wqkvb  = (unsigned short*)(ws + 8388608);    //  6 MB
  unsigned short* wprojb = (unsigned short*)(ws + 14680064);   //  2 MB
  unsigned short* Qb     = (unsigned short*)(ws + 16777216);   //  8 MB
  unsigned short* Kb     = (unsigned short*)(ws + 25165824);   //  8 MB
  unsigned short* Vtb    = (unsigned short*)(ws + 41943040);   //  8 MB
  unsigned short* aob    = (unsigned short*)(ws + 50331648);   //  8 MB
  float*          Op     = (float*)(ws + 58720256);            // 32 MB
  float*          lp     = (float*)(ws + 92274688);            // 0.5 MB

  k_cvt<<<8192, 256, 0, stream>>>(x, w_qkv, w_proj, xb, wqkvb, wprojb);

  k_gemm_qkv<<<dim3(24, 32), 256, 0, stream>>>(xb, wqkvb, b_qkv, fcos, fsin,
                                               Qb, Kb, Vtb);

  k_attn<<<1024, 256, 0, stream>>>(Qb, Kb, Vtb, Op, lp);
  k_combine<<<4096, 256, 0, stream>>>(Op, lp, aob);

  k_gemm_proj<<<dim3(8, 64), 256, 0, stream>>>(aob, wprojb, b_proj, out);
}

// Round 8
// 226.650 us; speedup vs baseline: 1.0569x; 1.0569x over previous
//
#include <hip/hip_runtime.h>
#include <hip/hip_bf16.h>
#include <stdint.h>

#define BB 2
#define NN 2048
#define CC 1024
#define HH 16
#define DD 64
#define C3 3072

typedef __attribute__((ext_vector_type(8))) short bf16x8;
typedef __attribute__((ext_vector_type(4))) float f32x4;
typedef __attribute__((ext_vector_type(4))) unsigned short ushort4_t;

__device__ __forceinline__ unsigned short f2bf(float f) {
  union { float f; unsigned u; } v; v.f = f;
  unsigned r = v.u + 0x7FFFu + ((v.u >> 16) & 1u);
  return (unsigned short)(r >> 16);
}

#if __has_builtin(__builtin_amdgcn_exp2f)
#define EXP2(x) __builtin_amdgcn_exp2f(x)
#else
#define EXP2(x) exp2f(x)
#endif

// 0.125 (1/sqrt(D)) * log2(e): folded into Q so softmax is raw v_exp_f32 (2^x)
#define QSCALE 0.18033688f

// async global->LDS, 16B per lane; LDS dest must be wave-uniform base + lane*16
#define GLDS(g, l) __builtin_amdgcn_global_load_lds( \
    (const __attribute__((address_space(1))) void*)(g), \
    (__attribute__((address_space(3))) void*)(l), 16, 0, 0)

// ----------------------------------------- merged fp32->bf16 converts (3 bufs)
__global__ __launch_bounds__(256) void k_cvt(
    const float* __restrict__ x, const float* __restrict__ wq,
    const float* __restrict__ wp,
    unsigned short* __restrict__ xb, unsigned short* __restrict__ wqb,
    unsigned short* __restrict__ wpb)
{
  int blk = blockIdx.x;
  const float* s; unsigned short* d; int i;
  if (blk < 4096)      { s = x;  d = xb;  i = blk * 256 + threadIdx.x; }
  else if (blk < 7168) { s = wq; d = wqb; i = (blk - 4096) * 256 + threadIdx.x; }
  else                 { s = wp; d = wpb; i = (blk - 7168) * 256 + threadIdx.x; }
  float4 v = ((const float4*)s)[i];
  ushort4_t o;
  o.x = f2bf(v.x); o.y = f2bf(v.y); o.z = f2bf(v.z); o.w = f2bf(v.w);
  ((ushort4_t*)d)[i] = o;
}

// -------------------------------- GEMM1 fused: qkv = x@Wqkv^T + b, RoPE, pack
// BK=32, DOUBLE-BUFFERED staging, ONE barrier/iter (attention-v3 transform:
// loads for tile k+1 in flight across the whole compute of tile k).
// Epilogue (proven in R6): RoPE in registers (shfl_xor pair), wave-private
// LDS tile (reusing staging LDS after a barrier), 8 contiguous dwordx4 stores
// per wave. Region V staged transposed -> writes Vt[bh][d][n] directly.
__global__ __launch_bounds__(256) void k_gemm_qkv(
    const unsigned short* __restrict__ A, const unsigned short* __restrict__ Bt,
    const float* __restrict__ bias,
    const float* __restrict__ cosb, const float* __restrict__ sinb,
    unsigned short* __restrict__ Qg, unsigned short* __restrict__ Kg,
    unsigned short* __restrict__ Vt)
{
  __shared__ __align__(16) unsigned short Sh[16384];  // 32KB: 2x(As+Bs) / epilogue
  const int tid  = threadIdx.x;
  const int lane = tid & 63;
  const int wave = tid >> 6;
  const int bm = blockIdx.y * 128;
  const int bn = blockIdx.x * 128;
  const int wm = (wave >> 1) * 64;
  const int wn = (wave & 1) * 64;
  const int frow = lane & 15;
  const int fk   = (lane >> 4) * 8;
  const int K = 1024;
  const int NIT = K / 32;

  f32x4 acc[4][4] = {};

  const int row0 = tid >> 2, cc0 = tid & 3;
  const int row1 = row0 + 64;
  const unsigned short* Arow0 = A  + (size_t)(bm + row0) * K + cc0 * 8;
  const unsigned short* Arow1 = A  + (size_t)(bm + row1) * K + cc0 * 8;
  const unsigned short* Brow0 = Bt + (size_t)(bn + row0) * K + cc0 * 8;
  const unsigned short* Brow1 = Bt + (size_t)(bn + row1) * K + cc0 * 8;

  // stage iter 0 into buffer 0
  GLDS(Arow0, Sh + (size_t)tid * 8);
  GLDS(Brow0, Sh + 4096 + (size_t)tid * 8);
  GLDS(Arow1, Sh + (size_t)(tid + 256) * 8);
  GLDS(Brow1, Sh + 4096 + (size_t)(tid + 256) * 8);

  for (int it = 0; it < NIT; ++it) {
    const int p = it & 1;
    const unsigned short* As = Sh + p * 8192;
    const unsigned short* Bs = As + 4096;
    __syncthreads();   // drains buffer-p loads (issued a full iteration ago)

    if (it + 1 < NIT) {
      const int k1 = (it + 1) * 32;
      unsigned short* An = Sh + (1 - p) * 8192;
      GLDS(Arow0 + k1, An + (size_t)tid * 8);
      GLDS(Brow0 + k1, An + 4096 + (size_t)tid * 8);
      GLDS(Arow1 + k1, An + (size_t)(tid + 256) * 8);
      GLDS(Brow1 + k1, An + 4096 + (size_t)(tid + 256) * 8);
    }

    bf16x8 af[4], bfr[4];
#pragma unroll
    for (int t = 0; t < 4; ++t) {
      af[t]  = *(const bf16x8*)(As + (wm + t * 16 + frow) * 32 + fk);
      bfr[t] = *(const bf16x8*)(Bs + (wn + t * 16 + frow) * 32 + fk);
    }
#pragma unroll
    for (int mt = 0; mt < 4; ++mt)
#pragma unroll
      for (int nt = 0; nt < 4; ++nt)
        acc[mt][nt] = __builtin_amdgcn_mfma_f32_16x16x32_bf16(af[mt], bfr[nt], acc[mt][nt], 0, 0, 0);
  }
  __syncthreads();   // all waves done with staging LDS -> reusable for epilogue

  const int er0  = (lane >> 4) * 4;
  const int ecol = lane & 15;
  const int region = bn >> 10;                 // wave-uniform: 0=Q,1=K,2=V
  const int gcol0 = bn + wn;                   // 64-aligned -> one head
  const int h  = (gcol0 >> 6) & 15;
  const int rowg0 = bm + wm;                   // wave-uniform
  const int b  = rowg0 >> 11;
  const int n0 = rowg0 & (NN - 1);
  unsigned short* wt = Sh + wave * 4096;       // 64x64 wave-private tile

#pragma unroll
  for (int nt = 0; nt < 4; ++nt) {
    const int c64 = nt * 16 + ecol;            // d within head
    const float bv = bias[gcol0 + c64];
    const int ii  = c64 >> 1;
#pragma unroll
    for (int mt = 0; mt < 4; ++mt)
#pragma unroll
      for (int r = 0; r < 4; ++r) {
        const int ml = mt * 16 + er0 + r;      // row within wave tile
        const int n  = n0 + ml;
        float v = acc[mt][nt][r] + bv;
        float vp = __shfl_xor(v, 1, 64);       // pair partner (d^1)
        if (region == 2) {
          // transposed tile [d][m], chunk over m swizzled by d
          wt[c64 * 64 + ((((ml >> 3) ^ (c64 & 7)) << 3) | (ml & 7))] = f2bf(v);
        } else {
          float cth = cosb[n * 32 + ii], sth = sinb[n * 32 + ii];
          float ov = (c64 & 1) ? (vp * sth + v * cth)
                               : (v * cth - vp * sth);
          if (region == 0) ov *= QSCALE;
          // tile [m][d], chunk over d swizzled by m
          wt[ml * 64 + ((((c64 >> 3) ^ (ml & 7)) << 3) | (c64 & 7))] = f2bf(ov);
        }
      }
  }

  // coalesced store phase (wave-private tile; in-wave lgkmcnt ordering)
  const int rr = lane >> 3, cc = lane & 7;
  if (region == 2) {
    unsigned short* dst = Vt + (size_t)(b * HH + h) * DD * NN + n0;
#pragma unroll
    for (int it = 0; it < 8; ++it) {
      int dl = it * 8 + rr;                    // d-row of Vt
      bf16x8 vv = *(const bf16x8*)(wt + dl * 64 + ((cc ^ (dl & 7)) << 3));
      *(bf16x8*)(dst + (size_t)dl * NN + cc * 8) = vv;
    }
  } else {
    unsigned short* dqk = ((region == 0) ? Qg : Kg) +
                          ((size_t)(b * HH + h) * NN + n0) * DD;
#pragma unroll
    for (int it = 0; it < 8; ++it) {
      int ml = it * 8 + rr;                    // n-row
      bf16x8 vv = *(const bf16x8*)(wt + ml * 64 + ((cc ^ (ml & 7)) << 3));
      *(bf16x8*)(dqk + (size_t)ml * DD + cc * 8) = vv;
    }
  }
}

// ----------------------------------------------------- flash attention v5
// (R4 config — best measured; kv-split reverted per R6 post-mortem.)
// 32 q-rows/wave, grid 512 (128 q/block), 48KB LDS, 2 blocks/CU.
// Double-buffered Ks/Vs, one barrier/iter; Ps wave-private; row-sums via
// ones-MFMA; p = 2^s (scale folded into Q); truncating bf16 P store.
__global__ __launch_bounds__(256) void k_attn(
    const unsigned short* __restrict__ Qg, const unsigned short* __restrict__ Kg,
    const unsigned short* __restrict__ Vtg, unsigned short* __restrict__ Og)
{
  __shared__ __align__(16) unsigned short Ks[2][64 * 64];
  __shared__ __align__(16) unsigned short Vs[2][64 * 64];
  __shared__ __align__(16) unsigned short Ps[4][32 * 64];

  const int tid  = threadIdx.x;
  const int lane = tid & 63;
  const int wave = tid >> 6;
  const int bh = blockIdx.x >> 4;     // 16 q-tiles of 128 per bh
  const int qt = blockIdx.x & 15;
  const int q0 = qt * 128 + wave * 32;
  const int frow   = lane & 15;
  const int fchunk = lane >> 4;
  const int er0  = (lane >> 4) * 4;
  const int ecol = lane & 15;

  const unsigned short* Qb = Qg  + (size_t)bh * NN * DD;
  const unsigned short* Kb = Kg  + (size_t)bh * NN * DD;
  const unsigned short* Vb = Vtg + (size_t)bh * DD * NN;

  bf16x8 qf[2][2];
#pragma unroll
  for (int m = 0; m < 2; ++m)
#pragma unroll
    for (int kt = 0; kt < 2; ++kt)
      qf[m][kt] = *(const bf16x8*)(Qb + (size_t)(q0 + m * 16 + frow) * DD + kt * 32 + fchunk * 8);

  bf16x8 ones;
#pragma unroll
  for (int i = 0; i < 8; ++i) ones[i] = (short)0x3F80;

  f32x4 oacc[2][4] = {};
  f32x4 lacc[2] = {};

  const int row0 = tid >> 3, cc0 = tid & 7;
  const int sw0 = (cc0 ^ (row0 & 7)) * 8;

  GLDS(Kb + (size_t)row0 * DD + sw0,        Ks[0] + (size_t)tid * 8);
  GLDS(Vb + (size_t)row0 * NN + sw0,        Vs[0] + (size_t)tid * 8);
  GLDS(Kb + (size_t)(row0 + 32) * DD + sw0, Ks[0] + (size_t)(tid + 256) * 8);
  GLDS(Vb + (size_t)(row0 + 32) * NN + sw0, Vs[0] + (size_t)(tid + 256) * 8);

  for (int t = 0; t < NN / 64; ++t) {
    const int p = t & 1;
    __syncthreads();

    if (t + 1 < NN / 64) {
      const int j = (t + 1) * 64;
      GLDS(Kb + (size_t)(j + row0) * DD + sw0,      Ks[1 - p] + (size_t)tid * 8);
      GLDS(Vb + (size_t)row0 * NN + j + sw0,        Vs[1 - p] + (size_t)tid * 8);
      GLDS(Kb + (size_t)(j + row0 + 32) * DD + sw0, Ks[1 - p] + (size_t)(tid + 256) * 8);
      GLDS(Vb + (size_t)(row0 + 32) * NN + j + sw0, Vs[1 - p] + (size_t)(tid + 256) * 8);
    }

    // S = Q K^T : 2 m-frags x 4 kv-frags; K frags read once, used twice
    f32x4 sacc[2][4] = {};
#pragma unroll
    for (int nt = 0; nt < 4; ++nt) {
      int kr = nt * 16 + frow;
      bf16x8 kf0 = *(const bf16x8*)(Ks[p] + kr * 64 + ((fchunk       ^ (kr & 7)) << 3));
      bf16x8 kf1 = *(const bf16x8*)(Ks[p] + kr * 64 + (((fchunk + 4) ^ (kr & 7)) << 3));
#pragma unroll
      for (int m = 0; m < 2; ++m) {
        sacc[m][nt] = __builtin_amdgcn_mfma_f32_16x16x32_bf16(qf[m][0], kf0, sacc[m][nt], 0, 0, 0);
        sacc[m][nt] = __builtin_amdgcn_mfma_f32_16x16x32_bf16(qf[m][1], kf1, sacc[m][nt], 0, 0, 0);
      }
    }

    // p = 2^s; truncating bf16 store into wave-private Ps
#pragma unroll
    for (int m = 0; m < 2; ++m)
#pragma unroll
      for (int r = 0; r < 4; ++r) {
        int prow = m * 16 + er0 + r;
#pragma unroll
        for (int nt = 0; nt < 4; ++nt) {
          float pv = EXP2(sacc[m][nt][r]);
          union { float f; unsigned u; } cv; cv.f = pv;
          int col = nt * 16 + ecol;
          Ps[wave][prow * 64 + (((col >> 3) ^ (prow & 7)) << 3) + (col & 7)] =
              (unsigned short)(cv.u >> 16);
        }
      }

    // O += P V ; l += P @ 1 ; V frags read once, used for both m-frags
    bf16x8 pf0[2], pf1[2];
#pragma unroll
    for (int m = 0; m < 2; ++m) {
      int pr = m * 16 + frow;
      pf0[m] = *(const bf16x8*)(&Ps[wave][pr * 64 + ((fchunk       ^ (pr & 7)) << 3)]);
      pf1[m] = *(const bf16x8*)(&Ps[wave][pr * 64 + (((fchunk + 4) ^ (pr & 7)) << 3)]);
      lacc[m] = __builtin_amdgcn_mfma_f32_16x16x32_bf16(pf0[m], ones, lacc[m], 0, 0, 0);
      lacc[m] = __builtin_amdgcn_mfma_f32_16x16x32_bf16(pf1[m], ones, lacc[m], 0, 0, 0);
    }
#pragma unroll
    for (int dt = 0; dt < 4; ++dt) {
      int vr = dt * 16 + frow;
      bf16x8 vf0 = *(const bf16x8*)(Vs[p] + vr * 64 + ((fchunk       ^ (vr & 7)) << 3));
      bf16x8 vf1 = *(const bf16x8*)(Vs[p] + vr * 64 + (((fchunk + 4) ^ (vr & 7)) << 3));
#pragma unroll
      for (int m = 0; m < 2; ++m) {
        oacc[m][dt] = __builtin_amdgcn_mfma_f32_16x16x32_bf16(pf0[m], vf0, oacc[m][dt], 0, 0, 0);
        oacc[m][dt] = __builtin_amdgcn_mfma_f32_16x16x32_bf16(pf1[m], vf1, oacc[m][dt], 0, 0, 0);
      }
    }
  }

  const int b = bh >> 4;
  const int h = bh & 15;
#pragma unroll
  for (int m = 0; m < 2; ++m)
#pragma unroll
    for (int dt = 0; dt < 4; ++dt)
#pragma unroll
      for (int r = 0; r < 4; ++r) {
        int qrow = q0 + m * 16 + er0 + r;
        int d = dt * 16 + ecol;
        float v = oacc[m][dt][r] / lacc[m][r];
        Og[(size_t)(b * NN + qrow) * CC + h * DD + d] = f2bf(v);
      }
}

// ------------------------------- GEMM2: out = aob @ Wproj^T + b (fp32 out)
// BK=32, double-buffered, one barrier/iter; 64x128 tiles, grid (8,64).
__global__ __launch_bounds__(256) void k_gemm_proj(
    const unsigned short* __restrict__ A, const unsigned short* __restrict__ Bt,
    const float* __restrict__ bias, float* __restrict__ Co)
{
  __shared__ __align__(16) unsigned short As[2][64 * 32];
  __shared__ __align__(16) unsigned short Bs[2][128 * 32];
  const int tid  = threadIdx.x;
  const int lane = tid & 63;
  const int wave = tid >> 6;
  const int bm = blockIdx.y * 64;
  const int bn = blockIdx.x * 128;
  const int wm = (wave >> 1) * 32;
  const int wn = (wave & 1) * 64;
  const int frow = lane & 15;
  const int fk   = (lane >> 4) * 8;
  const int K = 1024;
  const int NIT = K / 32;

  f32x4 acc[2][4] = {};

  const int row0 = tid >> 2, cc0 = tid & 3;
  const unsigned short* Arow  = A  + (size_t)(bm + row0) * K + cc0 * 8;
  const unsigned short* Brow0 = Bt + (size_t)(bn + row0) * K + cc0 * 8;
  const unsigned short* Brow1 = Bt + (size_t)(bn + row0 + 64) * K + cc0 * 8;

  GLDS(Arow,  As[0] + (size_t)tid * 8);
  GLDS(Brow0, Bs[0] + (size_t)tid * 8);
  GLDS(Brow1, Bs[0] + (size_t)(tid + 256) * 8);

  for (int it = 0; it < NIT; ++it) {
    const int p = it & 1;
    __syncthreads();

    if (it + 1 < NIT) {
      const int k1 = (it + 1) * 32;
      GLDS(Arow  + k1, As[1 - p] + (size_t)tid * 8);
      GLDS(Brow0 + k1, Bs[1 - p] + (size_t)tid * 8);
      GLDS(Brow1 + k1, Bs[1 - p] + (size_t)(tid + 256) * 8);
    }

    bf16x8 af[2], bfr[4];
#pragma unroll
    for (int t = 0; t < 2; ++t)
      af[t] = *(const bf16x8*)(As[p] + (wm + t * 16 + frow) * 32 + fk);
#pragma unroll
    for (int t = 0; t < 4; ++t)
      bfr[t] = *(const bf16x8*)(Bs[p] + (wn + t * 16 + frow) * 32 + fk);
#pragma unroll
    for (int mt = 0; mt < 2; ++mt)
#pragma unroll
      for (int nt = 0; nt < 4; ++nt)
        acc[mt][nt] = __builtin_amdgcn_mfma_f32_16x16x32_bf16(af[mt], bfr[nt], acc[mt][nt], 0, 0, 0);
  }

  const int er0  = (lane >> 4) * 4;
  const int ecol = lane & 15;
#pragma unroll
  for (int nt = 0; nt < 4; ++nt) {
    int col = bn + wn + nt * 16 + ecol;
    float bv = bias[col];
#pragma unroll
    for (int mt = 0; mt < 2; ++mt)
#pragma unroll
      for (int r = 0; r < 4; ++r) {
        int rowg = bm + wm + mt * 16 + er0 + r;
        Co[(size_t)rowg * CC + col] = acc[mt][nt][r] + bv;
      }
  }
}

// ---------------------------------------------------------------- launcher
extern "C" void kernel_launch(void* const* d_in, const int* in_sizes, int n_in,
                              void* d_out, int out_size, void* d_ws, size_t ws_size,
                              hipStream_t stream)
{
  const float* x      = (const float*)d_in[0];
  const float* w_qkv  = (const float*)d_in[1];
  const float* b_qkv  = (const float*)d_in[2];
  const float* w_proj = (const float*)d_in[3];
  const float* b_proj = (const float*)d_in[4];
  const float* fcos   = (const float*)d_in[5];
  const float* fsin   = (const float*)d_in[6];
  float* out = (float*)d_out;

  char* ws = (char*)d_ws;
  unsigned short* xb     = (unsigned short*)(ws);              //  8 MB
  unsigned short* wqkvb  = (unsigned short*)(ws + 8388608);    //  6 MB
  unsigned short* wprojb = (unsigned short*)(ws + 14680064);   //  2 MB
  unsigned short* Qb     = (unsigned short*)(ws + 16777216);   //  8 MB
  unsigned short* Kb     = (unsigned short*)(ws + 25165824);   //  8 MB
  unsigned short* Vtb    = (unsigned short*)(ws + 33554432);   //  8 MB
  unsigned short* aob    = (unsigned short*)(ws + 41943040);   //  8 MB

  k_cvt<<<8192, 256, 0, stream>>>(x, w_qkv, w_proj, xb, wqkvb, wprojb);

  k_gemm_qkv<<<dim3(24, 32), 256, 0, stream>>>(xb, wqkvb, b_qkv, fcos, fsin,
                                               Qb, Kb, Vtb);

  k_attn<<<512, 256, 0, stream>>>(Qb, Kb, Vtb, aob);

  k_gemm_proj<<<dim3(8, 64), 256, 0, stream>>>(aob, wprojb, b_proj, out);
}

// Round 9
// 212.457 us; speedup vs baseline: 1.1275x; 1.0668x over previous
//
#include <hip/hip_runtime.h>
#include <hip/hip_bf16.h>
#include <stdint.h>

#define BB 2
#define NN 2048
#define CC 1024
#define HH 16
#define DD 64
#define C3 3072

typedef __attribute__((ext_vector_type(8))) short bf16x8;
typedef __attribute__((ext_vector_type(4))) short bf16x4;
typedef __attribute__((ext_vector_type(4))) float f32x4;
typedef __attribute__((ext_vector_type(4))) unsigned short ushort4_t;

__device__ __forceinline__ unsigned short f2bf(float f) {
  union { float f; unsigned u; } v; v.f = f;
  unsigned r = v.u + 0x7FFFu + ((v.u >> 16) & 1u);
  return (unsigned short)(r >> 16);
}

#if __has_builtin(__builtin_amdgcn_exp2f)
#define EXP2(x) __builtin_amdgcn_exp2f(x)
#else
#define EXP2(x) exp2f(x)
#endif

#if __has_builtin(__builtin_amdgcn_mfma_f32_16x16x16bf16_1k)
#define HAVE_MFMA16 1
#endif

// truncating pack of two f32 -> one VGPR holding {lo16=hi(a), hi16=hi(b)}
__device__ __forceinline__ unsigned pack_bf2(float a, float b) {
  union { float f; unsigned u; } ua, ub; ua.f = a; ub.f = b;
#if __has_builtin(__builtin_amdgcn_perm)
  return __builtin_amdgcn_perm(ub.u, ua.u, 0x07060302u);
#else
  return (ua.u >> 16) | (ub.u & 0xFFFF0000u);
#endif
}

// 0.125 (1/sqrt(D)) * log2(e): folded into Q so softmax is raw v_exp_f32 (2^x)
#define QSCALE 0.18033688f

// async global->LDS, 16B per lane; LDS dest must be wave-uniform base + lane*16
#define GLDS(g, l) __builtin_amdgcn_global_load_lds( \
    (const __attribute__((address_space(1))) void*)(g), \
    (__attribute__((address_space(3))) void*)(l), 16, 0, 0)

// ----------------------------------------- merged fp32->bf16 converts (3 bufs)
__global__ __launch_bounds__(256) void k_cvt(
    const float* __restrict__ x, const float* __restrict__ wq,
    const float* __restrict__ wp,
    unsigned short* __restrict__ xb, unsigned short* __restrict__ wqb,
    unsigned short* __restrict__ wpb)
{
  int blk = blockIdx.x;
  const float* s; unsigned short* d; int i;
  if (blk < 4096)      { s = x;  d = xb;  i = blk * 256 + threadIdx.x; }
  else if (blk < 7168) { s = wq; d = wqb; i = (blk - 4096) * 256 + threadIdx.x; }
  else                 { s = wp; d = wpb; i = (blk - 7168) * 256 + threadIdx.x; }
  float4 v = ((const float4*)s)[i];
  ushort4_t o;
  o.x = f2bf(v.x); o.y = f2bf(v.y); o.z = f2bf(v.z); o.w = f2bf(v.w);
  ((ushort4_t*)d)[i] = o;
}

// -------------------------------- GEMM1 fused: qkv = x@Wqkv^T + b, RoPE, pack
// BK=32, double-buffered, one barrier/iter. Epilogue: RoPE in registers,
// wave-private LDS tile (staging LDS reused), 8 contiguous dwordx4 stores per
// wave. Region V staged transposed -> writes Vt[bh][d][n] directly.
__global__ __launch_bounds__(256) void k_gemm_qkv(
    const unsigned short* __restrict__ A, const unsigned short* __restrict__ Bt,
    const float* __restrict__ bias,
    const float* __restrict__ cosb, const float* __restrict__ sinb,
    unsigned short* __restrict__ Qg, unsigned short* __restrict__ Kg,
    unsigned short* __restrict__ Vt)
{
  __shared__ __align__(16) unsigned short Sh[16384];  // 32KB: 2x(As+Bs) / epilogue
  const int tid  = threadIdx.x;
  const int lane = tid & 63;
  const int wave = tid >> 6;
  const int bm = blockIdx.y * 128;
  const int bn = blockIdx.x * 128;
  const int wm = (wave >> 1) * 64;
  const int wn = (wave & 1) * 64;
  const int frow = lane & 15;
  const int fk   = (lane >> 4) * 8;
  const int K = 1024;
  const int NIT = K / 32;

  f32x4 acc[4][4] = {};

  const int row0 = tid >> 2, cc0 = tid & 3;
  const int row1 = row0 + 64;
  const unsigned short* Arow0 = A  + (size_t)(bm + row0) * K + cc0 * 8;
  const unsigned short* Arow1 = A  + (size_t)(bm + row1) * K + cc0 * 8;
  const unsigned short* Brow0 = Bt + (size_t)(bn + row0) * K + cc0 * 8;
  const unsigned short* Brow1 = Bt + (size_t)(bn + row1) * K + cc0 * 8;

  GLDS(Arow0, Sh + (size_t)tid * 8);
  GLDS(Brow0, Sh + 4096 + (size_t)tid * 8);
  GLDS(Arow1, Sh + (size_t)(tid + 256) * 8);
  GLDS(Brow1, Sh + 4096 + (size_t)(tid + 256) * 8);

  for (int it = 0; it < NIT; ++it) {
    const int p = it & 1;
    const unsigned short* As = Sh + p * 8192;
    const unsigned short* Bs = As + 4096;
    __syncthreads();

    if (it + 1 < NIT) {
      const int k1 = (it + 1) * 32;
      unsigned short* An = Sh + (1 - p) * 8192;
      GLDS(Arow0 + k1, An + (size_t)tid * 8);
      GLDS(Brow0 + k1, An + 4096 + (size_t)tid * 8);
      GLDS(Arow1 + k1, An + (size_t)(tid + 256) * 8);
      GLDS(Brow1 + k1, An + 4096 + (size_t)(tid + 256) * 8);
    }

    bf16x8 af[4], bfr[4];
#pragma unroll
    for (int t = 0; t < 4; ++t) {
      af[t]  = *(const bf16x8*)(As + (wm + t * 16 + frow) * 32 + fk);
      bfr[t] = *(const bf16x8*)(Bs + (wn + t * 16 + frow) * 32 + fk);
    }
#pragma unroll
    for (int mt = 0; mt < 4; ++mt)
#pragma unroll
      for (int nt = 0; nt < 4; ++nt)
        acc[mt][nt] = __builtin_amdgcn_mfma_f32_16x16x32_bf16(af[mt], bfr[nt], acc[mt][nt], 0, 0, 0);
  }
  __syncthreads();   // staging LDS now reusable for epilogue

  const int er0  = (lane >> 4) * 4;
  const int ecol = lane & 15;
  const int region = bn >> 10;                 // wave-uniform: 0=Q,1=K,2=V
  const int gcol0 = bn + wn;                   // 64-aligned -> one head
  const int h  = (gcol0 >> 6) & 15;
  const int rowg0 = bm + wm;                   // wave-uniform
  const int b  = rowg0 >> 11;
  const int n0 = rowg0 & (NN - 1);
  unsigned short* wt = Sh + wave * 4096;       // 64x64 wave-private tile

#pragma unroll
  for (int nt = 0; nt < 4; ++nt) {
    const int c64 = nt * 16 + ecol;            // d within head
    const float bv = bias[gcol0 + c64];
    const int ii  = c64 >> 1;
#pragma unroll
    for (int mt = 0; mt < 4; ++mt)
#pragma unroll
      for (int r = 0; r < 4; ++r) {
        const int ml = mt * 16 + er0 + r;      // row within wave tile
        const int n  = n0 + ml;
        float v = acc[mt][nt][r] + bv;
        float vp = __shfl_xor(v, 1, 64);       // pair partner (d^1)
        if (region == 2) {
          wt[c64 * 64 + ((((ml >> 3) ^ (c64 & 7)) << 3) | (ml & 7))] = f2bf(v);
        } else {
          float cth = cosb[n * 32 + ii], sth = sinb[n * 32 + ii];
          float ov = (c64 & 1) ? (vp * sth + v * cth)
                               : (v * cth - vp * sth);
          if (region == 0) ov *= QSCALE;
          wt[ml * 64 + ((((c64 >> 3) ^ (ml & 7)) << 3) | (c64 & 7))] = f2bf(ov);
        }
      }
  }

  const int rr = lane >> 3, cc = lane & 7;
  if (region == 2) {
    unsigned short* dst = Vt + (size_t)(b * HH + h) * DD * NN + n0;
#pragma unroll
    for (int it = 0; it < 8; ++it) {
      int dl = it * 8 + rr;
      bf16x8 vv = *(const bf16x8*)(wt + dl * 64 + ((cc ^ (dl & 7)) << 3));
      *(bf16x8*)(dst + (size_t)dl * NN + cc * 8) = vv;
    }
  } else {
    unsigned short* dqk = ((region == 0) ? Qg : Kg) +
                          ((size_t)(b * HH + h) * NN + n0) * DD;
#pragma unroll
    for (int it = 0; it < 8; ++it) {
      int ml = it * 8 + rr;
      bf16x8 vv = *(const bf16x8*)(wt + ml * 64 + ((cc ^ (ml & 7)) << 3));
      *(bf16x8*)(dqk + (size_t)ml * DD + cc * 8) = vv;
    }
  }
}

// ----------------------------------------------------- flash attention v7
// REGISTER-P: compute S^T = K·Q^T (swap MFMA operands) so Sc exits in the
// exact A-operand layout of 16x16x16 MFMA (m=lane&15=q, k=quad*4+j=kv).
// exp + v_perm pack in registers -> PV via mfma_f32_16x16x16bf16_1k.
// No Ps LDS, no P round-trip, no ones-MFMA (l accumulated per-lane, reduced
// once at epilogue via shfl_xor). Double-buffered Ks/Vs, one barrier/iter.
// 32 q-rows/wave, grid 512 (128 q/block), 32KB LDS.
__global__ __launch_bounds__(256) void k_attn(
    const unsigned short* __restrict__ Qg, const unsigned short* __restrict__ Kg,
    const unsigned short* __restrict__ Vtg, unsigned short* __restrict__ Og)
{
  __shared__ __align__(16) unsigned short Ks[2][64 * 64];
  __shared__ __align__(16) unsigned short Vs[2][64 * 64];
#ifndef HAVE_MFMA16
  __shared__ __align__(16) unsigned short Ps[4][32 * 64];
#endif

  const int tid  = threadIdx.x;
  const int lane = tid & 63;
  const int wave = tid >> 6;
  const int bh = blockIdx.x >> 4;
  const int qt = blockIdx.x & 15;
  const int q0 = qt * 128 + wave * 32;
  const int frow   = lane & 15;
  const int fchunk = lane >> 4;
  const int er0  = (lane >> 4) * 4;
  const int ecol = lane & 15;

  const unsigned short* Qb = Qg  + (size_t)bh * NN * DD;
  const unsigned short* Kb = Kg  + (size_t)bh * NN * DD;
  const unsigned short* Vb = Vtg + (size_t)bh * DD * NN;

  bf16x8 qf[2][2];
#pragma unroll
  for (int m = 0; m < 2; ++m)
#pragma unroll
    for (int kt = 0; kt < 2; ++kt)
      qf[m][kt] = *(const bf16x8*)(Qb + (size_t)(q0 + m * 16 + frow) * DD + kt * 32 + fchunk * 8);

  f32x4 oacc[2][4] = {};

  const int row0 = tid >> 3, cc0 = tid & 7;
  const int sw0 = (cc0 ^ (row0 & 7)) * 8;

  GLDS(Kb + (size_t)row0 * DD + sw0,        Ks[0] + (size_t)tid * 8);
  GLDS(Vb + (size_t)row0 * NN + sw0,        Vs[0] + (size_t)tid * 8);
  GLDS(Kb + (size_t)(row0 + 32) * DD + sw0, Ks[0] + (size_t)(tid + 256) * 8);
  GLDS(Vb + (size_t)(row0 + 32) * NN + sw0, Vs[0] + (size_t)(tid + 256) * 8);

#ifdef HAVE_MFMA16
  float lsum[2] = {0.f, 0.f};

  for (int t = 0; t < NN / 64; ++t) {
    const int p = t & 1;
    __syncthreads();

    if (t + 1 < NN / 64) {
      const int j = (t + 1) * 64;
      GLDS(Kb + (size_t)(j + row0) * DD + sw0,      Ks[1 - p] + (size_t)tid * 8);
      GLDS(Vb + (size_t)row0 * NN + j + sw0,        Vs[1 - p] + (size_t)tid * 8);
      GLDS(Kb + (size_t)(j + row0 + 32) * DD + sw0, Ks[1 - p] + (size_t)(tid + 256) * 8);
      GLDS(Vb + (size_t)(row0 + 32) * NN + j + sw0, Vs[1 - p] + (size_t)(tid + 256) * 8);
    }

    // S^T = K Q^T : A = K-frag (m=kv), B = Q-frag (n=q)
    f32x4 sacc[2][4] = {};
#pragma unroll
    for (int nt = 0; nt < 4; ++nt) {
      int kr = nt * 16 + frow;
      bf16x8 kf0 = *(const bf16x8*)(Ks[p] + kr * 64 + ((fchunk       ^ (kr & 7)) << 3));
      bf16x8 kf1 = *(const bf16x8*)(Ks[p] + kr * 64 + (((fchunk + 4) ^ (kr & 7)) << 3));
#pragma unroll
      for (int m = 0; m < 2; ++m) {
        sacc[m][nt] = __builtin_amdgcn_mfma_f32_16x16x32_bf16(kf0, qf[m][0], sacc[m][nt], 0, 0, 0);
        sacc[m][nt] = __builtin_amdgcn_mfma_f32_16x16x32_bf16(kf1, qf[m][1], sacc[m][nt], 0, 0, 0);
      }
    }

    // exp in registers; pack to bf16 A-frags; accumulate l per-lane
    bf16x4 pfr[2][4];
#pragma unroll
    for (int m = 0; m < 2; ++m)
#pragma unroll
      for (int nt = 0; nt < 4; ++nt) {
        float e0 = EXP2(sacc[m][nt][0]);
        float e1 = EXP2(sacc[m][nt][1]);
        float e2 = EXP2(sacc[m][nt][2]);
        float e3 = EXP2(sacc[m][nt][3]);
        lsum[m] += (e0 + e1) + (e2 + e3);
        union { unsigned u[2]; bf16x4 v; } pk;
        pk.u[0] = pack_bf2(e0, e1);
        pk.u[1] = pack_bf2(e2, e3);
        pfr[m][nt] = pk.v;
      }

    // O += P V : A = P (regs), B = V[kv][d] from Vt rows (b64 frags)
#pragma unroll
    for (int dt = 0; dt < 4; ++dt) {
      int vr = dt * 16 + frow;
      bf16x4 vfr[4];
#pragma unroll
      for (int c = 0; c < 4; ++c)
        vfr[c] = *(const bf16x4*)(Vs[p] + vr * 64 +
                   (((2 * c + (fchunk >> 1)) ^ (vr & 7)) << 3) + (fchunk & 1) * 4);
#pragma unroll
      for (int m = 0; m < 2; ++m)
#pragma unroll
        for (int c = 0; c < 4; ++c)
          oacc[m][dt] = __builtin_amdgcn_mfma_f32_16x16x16bf16_1k(pfr[m][c], vfr[c], oacc[m][dt], 0, 0, 0);
    }
  }

  // epilogue: reduce l across quads, then normalize + store
  const int b = bh >> 4;
  const int h = bh & 15;
#pragma unroll
  for (int m = 0; m < 2; ++m) {
    lsum[m] += __shfl_xor(lsum[m], 16, 64);
    lsum[m] += __shfl_xor(lsum[m], 32, 64);   // lane holds l[q=lane&15] of tile m
    float linv[4];
#pragma unroll
    for (int r = 0; r < 4; ++r)
      linv[r] = 1.0f / __shfl(lsum[m], er0 + r, 64);
#pragma unroll
    for (int dt = 0; dt < 4; ++dt)
#pragma unroll
      for (int r = 0; r < 4; ++r) {
        int qrow = q0 + m * 16 + er0 + r;
        int d = dt * 16 + ecol;
        Og[(size_t)(b * NN + qrow) * CC + h * DD + d] = f2bf(oacc[m][dt][r] * linv[r]);
      }
  }

#else  // fallback: proven v5 LDS-P path
  bf16x8 ones;
#pragma unroll
  for (int i = 0; i < 8; ++i) ones[i] = (short)0x3F80;
  f32x4 lacc[2] = {};

  for (int t = 0; t < NN / 64; ++t) {
    const int p = t & 1;
    __syncthreads();
    if (t + 1 < NN / 64) {
      const int j = (t + 1) * 64;
      GLDS(Kb + (size_t)(j + row0) * DD + sw0,      Ks[1 - p] + (size_t)tid * 8);
      GLDS(Vb + (size_t)row0 * NN + j + sw0,        Vs[1 - p] + (size_t)tid * 8);
      GLDS(Kb + (size_t)(j + row0 + 32) * DD + sw0, Ks[1 - p] + (size_t)(tid + 256) * 8);
      GLDS(Vb + (size_t)(row0 + 32) * NN + j + sw0, Vs[1 - p] + (size_t)(tid + 256) * 8);
    }
    f32x4 sacc[2][4] = {};
#pragma unroll
    for (int nt = 0; nt < 4; ++nt) {
      int kr = nt * 16 + frow;
      bf16x8 kf0 = *(const bf16x8*)(Ks[p] + kr * 64 + ((fchunk       ^ (kr & 7)) << 3));
      bf16x8 kf1 = *(const bf16x8*)(Ks[p] + kr * 64 + (((fchunk + 4) ^ (kr & 7)) << 3));
#pragma unroll
      for (int m = 0; m < 2; ++m) {
        sacc[m][nt] = __builtin_amdgcn_mfma_f32_16x16x32_bf16(qf[m][0], kf0, sacc[m][nt], 0, 0, 0);
        sacc[m][nt] = __builtin_amdgcn_mfma_f32_16x16x32_bf16(qf[m][1], kf1, sacc[m][nt], 0, 0, 0);
      }
    }
#pragma unroll
    for (int m = 0; m < 2; ++m)
#pragma unroll
      for (int r = 0; r < 4; ++r) {
        int prow = m * 16 + er0 + r;
#pragma unroll
        for (int nt = 0; nt < 4; ++nt) {
          float pv = EXP2(sacc[m][nt][r]);
          union { float f; unsigned u; } cv; cv.f = pv;
          int col = nt * 16 + ecol;
          Ps[wave][prow * 64 + (((col >> 3) ^ (prow & 7)) << 3) + (col & 7)] =
              (unsigned short)(cv.u >> 16);
        }
      }
    bf16x8 pf0[2], pf1[2];
#pragma unroll
    for (int m = 0; m < 2; ++m) {
      int pr = m * 16 + frow;
      pf0[m] = *(const bf16x8*)(&Ps[wave][pr * 64 + ((fchunk       ^ (pr & 7)) << 3)]);
      pf1[m] = *(const bf16x8*)(&Ps[wave][pr * 64 + (((fchunk + 4) ^ (pr & 7)) << 3)]);
      lacc[m] = __builtin_amdgcn_mfma_f32_16x16x32_bf16(pf0[m], ones, lacc[m], 0, 0, 0);
      lacc[m] = __builtin_amdgcn_mfma_f32_16x16x32_bf16(pf1[m], ones, lacc[m], 0, 0, 0);
    }
#pragma unroll
    for (int dt = 0; dt < 4; ++dt) {
      int vr = dt * 16 + frow;
      bf16x8 vf0 = *(const bf16x8*)(Vs[p] + vr * 64 + ((fchunk       ^ (vr & 7)) << 3));
      bf16x8 vf1 = *(const bf16x8*)(Vs[p] + vr * 64 + (((fchunk + 4) ^ (vr & 7)) << 3));
#pragma unroll
      for (int m = 0; m < 2; ++m) {
        oacc[m][dt] = __builtin_amdgcn_mfma_f32_16x16x32_bf16(pf0[m], vf0, oacc[m][dt], 0, 0, 0);
        oacc[m][dt] = __builtin_amdgcn_mfma_f32_16x16x32_bf16(pf1[m], vf1, oacc[m][dt], 0, 0, 0);
      }
    }
  }
  const int b = bh >> 4;
  const int h = bh & 15;
#pragma unroll
  for (int m = 0; m < 2; ++m)
#pragma unroll
    for (int dt = 0; dt < 4; ++dt)
#pragma unroll
      for (int r = 0; r < 4; ++r) {
        int qrow = q0 + m * 16 + er0 + r;
        int d = dt * 16 + ecol;
        Og[(size_t)(b * NN + qrow) * CC + h * DD + d] = f2bf(oacc[m][dt][r] / lacc[m][r]);
      }
#endif
}

// ------------------------------- GEMM2: out = aob @ Wproj^T + b (fp32 out)
// BK=32, double-buffered, one barrier/iter; 64x128 tiles, grid (8,64).
__global__ __launch_bounds__(256) void k_gemm_proj(
    const unsigned short* __restrict__ A, const unsigned short* __restrict__ Bt,
    const float* __restrict__ bias, float* __restrict__ Co)
{
  __shared__ __align__(16) unsigned short As[2][64 * 32];
  __shared__ __align__(16) unsigned short Bs[2][128 * 32];
  const int tid  = threadIdx.x;
  const int lane = tid & 63;
  const int wave = tid >> 6;
  const int bm = blockIdx.y * 64;
  const int bn = blockIdx.x * 128;
  const int wm = (wave >> 1) * 32;
  const int wn = (wave & 1) * 64;
  const int frow = lane & 15;
  const int fk   = (lane >> 4) * 8;
  const int K = 1024;
  const int NIT = K / 32;

  f32x4 acc[2][4] = {};

  const int row0 = tid >> 2, cc0 = tid & 3;
  const unsigned short* Arow  = A  + (size_t)(bm + row0) * K + cc0 * 8;
  const unsigned short* Brow0 = Bt + (size_t)(bn + row0) * K + cc0 * 8;
  const unsigned short* Brow1 = Bt + (size_t)(bn + row0 + 64) * K + cc0 * 8;

  GLDS(Arow,  As[0] + (size_t)tid * 8);
  GLDS(Brow0, Bs[0] + (size_t)tid * 8);
  GLDS(Brow1, Bs[0] + (size_t)(tid + 256) * 8);

  for (int it = 0; it < NIT; ++it) {
    const int p = it & 1;
    __syncthreads();

    if (it + 1 < NIT) {
      const int k1 = (it + 1) * 32;
      GLDS(Arow  + k1, As[1 - p] + (size_t)tid * 8);
      GLDS(Brow0 + k1, Bs[1 - p] + (size_t)tid * 8);
      GLDS(Brow1 + k1, Bs[1 - p] + (size_t)(tid + 256) * 8);
    }

    bf16x8 af[2], bfr[4];
#pragma unroll
    for (int t = 0; t < 2; ++t)
      af[t] = *(const bf16x8*)(As[p] + (wm + t * 16 + frow) * 32 + fk);
#pragma unroll
    for (int t = 0; t < 4; ++t)
      bfr[t] = *(const bf16x8*)(Bs[p] + (wn + t * 16 + frow) * 32 + fk);
#pragma unroll
    for (int mt = 0; mt < 2; ++mt)
#pragma unroll
      for (int nt = 0; nt < 4; ++nt)
        acc[mt][nt] = __builtin_amdgcn_mfma_f32_16x16x32_bf16(af[mt], bfr[nt], acc[mt][nt], 0, 0, 0);
  }

  const int er0  = (lane >> 4) * 4;
  const int ecol = lane & 15;
#pragma unroll
  for (int nt = 0; nt < 4; ++nt) {
    int col = bn + wn + nt * 16 + ecol;
    float bv = bias[col];
#pragma unroll
    for (int mt = 0; mt < 2; ++mt)
#pragma unroll
      for (int r = 0; r < 4; ++r) {
        int rowg = bm + wm + mt * 16 + er0 + r;
        Co[(size_t)rowg * CC + col] = acc[mt][nt][r] + bv;
      }
  }
}

// ---------------------------------------------------------------- launcher
extern "C" void kernel_launch(void* const* d_in, const int* in_sizes, int n_in,
                              void* d_out, int out_size, void* d_ws, size_t ws_size,
                              hipStream_t stream)
{
  const float* x      = (const float*)d_in[0];
  const float* w_qkv  = (const float*)d_in[1];
  const float* b_qkv  = (const float*)d_in[2];
  const float* w_proj = (const float*)d_in[3];
  const float* b_proj = (const float*)d_in[4];
  const float* fcos   = (const float*)d_in[5];
  const float* fsin   = (const float*)d_in[6];
  float* out = (float*)d_out;

  char* ws = (char*)d_ws;
  unsigned short* xb     = (unsigned short*)(ws);              //  8 MB
  unsigned short* wqkvb  = (unsigned short*)(ws + 8388608);    //  6 MB
  unsigned short* wprojb = (unsigned short*)(ws + 14680064);   //  2 MB
  unsigned short* Qb     = (unsigned short*)(ws + 16777216);   //  8 MB
  unsigned short* Kb     = (unsigned short*)(ws + 25165824);   //  8 MB
  unsigned short* Vtb    = (unsigned short*)(ws + 33554432);   //  8 MB
  unsigned short* aob    = (unsigned short*)(ws + 41943040);   //  8 MB

  k_cvt<<<8192, 256, 0, stream>>>(x, w_qkv, w_proj, xb, wqkvb, wprojb);

  k_gemm_qkv<<<dim3(24, 32), 256, 0, stream>>>(xb, wqkvb, b_qkv, fcos, fsin,
                                               Qb, Kb, Vtb);

  k_attn<<<512, 256, 0, stream>>>(Qb, Kb, Vtb, aob);

  k_gemm_proj<<<dim3(8, 64), 256, 0, stream>>>(aob, wprojb, b_proj, out);
}